// Round 13
// baseline (2029.904 us; speedup 1.0000x reference)
//
#include <hip/hip_runtime.h>

// ObjectMsgEncoder on MI355X. f32 I/O, bf16 MFMA internally (f32 accumulate).
// R12 -> R13: the lever never pulled: waves/block. All k_mega tilings since R9
// ran 8 waves (2/SIMD) and sat ~60-80% stalled; multi-block LDS co-residency
// never materialized (32KB -> 1 block). So:
//  * k_mega: 1024 thr / 16 waves (4/SIMD), same 64-row j-pair tile, Xb 32KB.
//    wave = (row-half rh, col-eighth ch): 2 row-frags x 2 col-frags, kt-chunks.
//  * k_rec: 1024 thr / 16 waves, wave = one 16-unit tile across all 4 gates
//    (32KB Whh slice/wave/step, 16 zxv loads/thread).

typedef __attribute__((ext_vector_type(8))) short short8;
typedef __attribute__((ext_vector_type(4))) float f32x4;

__device__ __forceinline__ float b2f(unsigned short u){
  union { unsigned int i; float f; } v; v.i = ((unsigned int)u) << 16; return v.f;
}
__device__ __forceinline__ unsigned short f2b(float f){
  union { float f; unsigned int i; } v; v.f = f;
  unsigned int i = v.i;
  unsigned int r = (i + 0x7FFFu + ((i >> 16) & 1u)) >> 16;
  return (unsigned short)r;
}
__device__ __forceinline__ float sigm(float x){ return 1.f/(1.f+__expf(-x)); }
__device__ __forceinline__ float tanh_f(float x){ float e = __expf(2.f*x); return 1.f - 2.f/(e+1.f); }
// Xb swizzle: 8-element (16B) chunks, phys chunk = (c&24) | ((c^row)&7).
__device__ __forceinline__ int xsw(int row, int n){
  int c = n >> 3;
  int pc = (c & 24) | ((c ^ row) & 7);
  return row*256 + pc*8 + (n & 7);
}
__device__ __forceinline__ int xchunk(int row, int c){
  return row*256 + ((c & 24) | ((c ^ row) & 7))*8;
}

#define MFMA16(a,b,c) __builtin_amdgcn_mfma_f32_16x16x32_bf16((a),(b),(c),0,0,0)

// ---------------- K0: f32 -> bf16 conversion of all 5 weight matrices ----------------
__global__ __launch_bounds__(256) void k_cvt5(const float* __restrict__ s0,
                                              const float* __restrict__ s1,
                                              const float* __restrict__ s2,
                                              const float* __restrict__ s3,
                                              const float* __restrict__ s4,
                                              unsigned short* __restrict__ dst){
  int i = blockIdx.x*256 + threadIdx.x;   // grid 3328*256 = 851,968 exactly
  const float* s; int off;
  if      (i < 262144){ s = s0; off = 0; }
  else if (i < 524288){ s = s1; off = 262144; }
  else if (i < 720896){ s = s2; off = 524288; }
  else if (i < 786432){ s = s3; off = 720896; }
  else                { s = s4; off = 786432; }
  dst[i] = f2b(s[i - off]);
}

// ---------------- K1: olf0 = emb * mask (f32 -> bf16) + zero outacc ----------------
__global__ __launch_bounds__(256) void k_prep(const float* __restrict__ emb,
                                              const int* __restrict__ counts,
                                              unsigned short* __restrict__ olf,
                                              float* __restrict__ outacc){
  int bs = blockIdx.x;            // b*28+s
  int b = bs / 28; int s = bs - b*28;
  int e = threadIdx.x;
  olf[(size_t)bs*256 + e] = (s < counts[b]) ? f2b(emb[(size_t)bs*256 + e]) : (unsigned short)0;
  outacc[(size_t)bs*256 + e] = 0.f;
}

// ---------------- K2a: zx = olf_l @ Wih^T  [7168,256]@[256,1024] -> bf16 ----------------
__global__ __launch_bounds__(256) void k_xgemm(const unsigned short* __restrict__ olf,
                                               const unsigned short* __restrict__ Wih,
                                               unsigned short* __restrict__ zx){
  const int tid = threadIdx.x;
  const int wid = tid >> 6, lane = tid & 63, col = lane & 15, quad = lane >> 4;
  const int m0 = blockIdx.x*64 + wid*16;
  short8 af[8];
  #pragma unroll
  for (int kt=0; kt<8; ++kt)
    af[kt] = *(const short8*)&olf[(size_t)(m0 + col)*256 + kt*32 + quad*8];
  #pragma unroll 4
  for (int nt=0; nt<64; ++nt){
    int n = nt*16 + col;
    f32x4 acc = (f32x4){0.f,0.f,0.f,0.f};
    #pragma unroll
    for (int kt=0; kt<8; ++kt){
      short8 bf = *(const short8*)&Wih[(size_t)n*256 + kt*32 + quad*8];
      acc = MFMA16(af[kt], bf, acc);
    }
    #pragma unroll
    for (int r=0; r<4; ++r)
      zx[(size_t)(m0 + quad*4 + r)*1024 + n] = f2b(acc[r]);
  }
}

// ---------------- K2b: LSTM recurrence (16 blocks x 16 scenes, 1024 thr) ----------------
// Wave wv (0..15) owns unit-tile u = wv*16+col across all 4 gates.
__global__ __launch_bounds__(1024) void k_rec(const unsigned short* __restrict__ zx,
                                              const unsigned short* __restrict__ Whh,
                                              const float* __restrict__ bih,
                                              const float* __restrict__ bhh,
                                              const int* __restrict__ counts,
                                              unsigned short* __restrict__ olf_out){
  __shared__ unsigned short Ab[16*264];   // [scene][unit 0..255], stride 264
  const int tid = threadIdx.x;
  const int wv = tid >> 6, lane = tid & 63, col = lane & 15, quad = lane >> 4;
  const int sc0 = blockIdx.x * 16;
  const int u = wv*16 + col;

  float bz[4];
  #pragma unroll
  for (int g=0; g<4; ++g) bz[g] = bih[g*256+u] + bhh[g*256+u];
  int cnt4[4];
  #pragma unroll
  for (int r=0; r<4; ++r) cnt4[r] = counts[sc0 + quad*4 + r];

  float cst[4];
  #pragma unroll
  for (int r=0; r<4; ++r) cst[r] = 0.f;
  for (int i=tid; i<16*264; i+=1024) Ab[i] = 0;   // h0 = 0
  __syncthreads();

  for (int t=0; t<28; ++t){
    float zxv[4][4];
    #pragma unroll
    for (int g=0; g<4; ++g){
      #pragma unroll
      for (int r=0; r<4; ++r)
        zxv[g][r] = b2f(zx[((size_t)(sc0 + quad*4 + r)*28 + t)*1024 + g*256 + u]);
    }
    f32x4 acc[4];
    #pragma unroll
    for (int g=0; g<4; ++g) acc[g] = (f32x4){0.f,0.f,0.f,0.f};
    #pragma unroll
    for (int kt=0; kt<8; ++kt){
      short8 a = *(const short8*)&Ab[col*264 + kt*32 + quad*8];
      #pragma unroll
      for (int g=0; g<4; ++g){
        short8 bf = *(const short8*)&Whh[(size_t)(g*256 + wv*16 + col)*256 + kt*32 + quad*8];
        acc[g] = MFMA16(a, bf, acc[g]);
      }
    }
    __syncthreads();   // all reads of Ab(t) done
    #pragma unroll
    for (int r=0; r<4; ++r){
      int s = quad*4 + r;
      float zi = acc[0][r] + zxv[0][r] + bz[0];
      float zf = acc[1][r] + zxv[1][r] + bz[1];
      float zg = acc[2][r] + zxv[2][r] + bz[2];
      float zo = acc[3][r] + zxv[3][r] + bz[3];
      float cc = sigm(zf)*cst[r] + sigm(zi)*tanh_f(zg);
      cst[r] = cc;
      float hh = sigm(zo)*tanh_f(cc);
      unsigned short hb = f2b(hh);
      Ab[s*264 + u] = hb;                                   // raw h feeds recurrence
      olf_out[((size_t)(sc0+s)*28 + t)*256 + u] = (t < cnt4[r]) ? hb : (unsigned short)0;
    }
    __syncthreads();
  }
}

// ---------------- K3: A-terms, [21504,256]@[256,512] -> bf16 ----------------
__global__ __launch_bounds__(256) void k_aterm(const unsigned short* __restrict__ olf,
                                               const unsigned short* __restrict__ Wgr,
                                               unsigned short* __restrict__ Aout){
  const int tid = threadIdx.x;
  const int wid = tid >> 6, lane = tid & 63, col = lane & 15, quad = lane >> 4;
  const int m0 = blockIdx.x*64 + wid*16;
  short8 af[8];
  #pragma unroll
  for (int kt=0; kt<8; ++kt)
    af[kt] = *(const short8*)&olf[(size_t)(m0 + col)*256 + kt*32 + quad*8];
  #pragma unroll 4
  for (int nt=0; nt<32; ++nt){
    int n = nt*16 + col;   // n<256: A_i (Wgr cols 0..255); else A_j (cols 256..511)
    const unsigned short* wb = (nt < 16) ? (Wgr + n*768) : (Wgr + (n-256)*768 + 256);
    f32x4 acc = (f32x4){0.f,0.f,0.f,0.f};
    #pragma unroll
    for (int kt=0; kt<8; ++kt){
      short8 bf = *(const short8*)&wb[kt*32 + quad*8];
      acc = MFMA16(af[kt], bf, acc);
    }
    #pragma unroll
    for (int r=0; r<4; ++r)
      Aout[(size_t)(m0 + quad*4 + r)*512 + nt*16 + col] = f2b(acc[r]);
  }
}

// ---------------- K4: fused per-(scene, j-pair) pipeline, 1024 thr / 16 waves ----------------
// Row p = i*2 + jc (i<28, jc<2) -> 56 rows padded to 64. Wave wv: row-half
// rh = wv&1 (rows rh*32..+31, 2 frags), col-eighth ch = wv>>1 (cols ch*32..+31,
// 2 frags). Xb = 64x256 bf16 = 32,768 B (stats in rows 56..63, epilogue-only).
#define GEMM_TILE64(WPTR, WSTRIDE, WOFF)                                            \
  {                                                                                 \
    Ya[0][0]=Ya[0][1]=Ya[1][0]=Ya[1][1]=(f32x4){0.f,0.f,0.f,0.f};                   \
    _Pragma("unroll 1")                                                             \
    for (int kc=0; kc<4; ++kc){                                                     \
      short8 av[2][2], bv[2][2];                                                    \
      _Pragma("unroll")                                                             \
      for (int uu=0; uu<2; ++uu){                                                   \
        int kt = kc*2 + uu; int c = kt*4 + quad;                                    \
        av[uu][0] = *(const short8*)&Xb[xchunk(rbase+col, c)];                      \
        av[uu][1] = *(const short8*)&Xb[xchunk(rbase+16+col, c)];                   \
        bv[uu][0] = *(const short8*)&(WPTR)[(nbase+col)*(WSTRIDE) + (WOFF) + kt*32 + quad*8];    \
        bv[uu][1] = *(const short8*)&(WPTR)[(nbase+16+col)*(WSTRIDE) + (WOFF) + kt*32 + quad*8]; \
      }                                                                             \
      _Pragma("unroll")                                                             \
      for (int uu=0; uu<2; ++uu){                                                   \
        Ya[0][0] = MFMA16(av[uu][0], bv[uu][0], Ya[0][0]);                          \
        Ya[1][0] = MFMA16(av[uu][1], bv[uu][0], Ya[1][0]);                          \
        Ya[0][1] = MFMA16(av[uu][0], bv[uu][1], Ya[0][1]);                          \
        Ya[1][1] = MFMA16(av[uu][1], bv[uu][1], Ya[1][1]);                          \
      }                                                                             \
    }                                                                               \
  }

__global__ __launch_bounds__(1024) void k_mega(
    const float* __restrict__ centers, const int* __restrict__ counts,
    const float* __restrict__ Wr, const float* __restrict__ br,
    const unsigned short* __restrict__ Wgr, const float* __restrict__ bgr,
    const unsigned short* __restrict__ Wbc, const float* __restrict__ bbc,
    const float* __restrict__ alpha,
    const unsigned short* __restrict__ Wesa, const float* __restrict__ besa,
    const float* __restrict__ Wmu, const float* __restrict__ bmu,
    const unsigned short* __restrict__ Aterm, float* __restrict__ outacc){
  __shared__ unsigned short Xb[64*256];    // 32,768 B; rows 56..63 = pad/stats
  float* lseBp = (float*)&Xb[56*256];      // 512 f32 [jc*256+o]
  float* gsbp  = (float*)&Xb[60*256];      // 64 f32 per row p
  float* lseGp = (float*)&Xb[60*256+128];  // 2 f32 per jc
  const int tid = threadIdx.x;
  const int wv = tid >> 6;          // 0..15
  const int rh = wv & 1;            // row half
  const int ch = wv >> 1;           // col eighth
  const int lane = tid & 63, col = lane & 15, quad = lane >> 4;
  const int b = blockIdx.x / 14, jt = blockIdx.x - b*14;   // j = jt*2 + jc
  const int cb = counts[b];
  const int rbase = rh*32;
  const int nbase = ch*32;

  float av_ = alpha[0];
  float tv = sigm(av_);
  float c1 = (1.f-tv)*(1.f-tv) + tv*tv;
  float c2 = 2.f*tv*(1.f-tv);

  int pis[2][4], pjs[2][4]; float pv[2][4];
  #pragma unroll
  for (int rf=0; rf<2; ++rf){
    #pragma unroll
    for (int r=0; r<4; ++r){
      int row = rbase + rf*16 + quad*4 + r;
      int i = row >> 1;
      pis[rf][r] = (i < 27) ? i : 27;
      pjs[rf][r] = jt*2 + (row & 1);
      pv[rf][r] = (row < 56 && i < cb && pjs[rf][r] < cb) ? 1.f : 0.f;
    }
  }
  // S0: rlf0[row] = (mask_i*c_i - mask_j*c_j) @ Wr^T + br ; pad rows = 0
  {
    int m = tid >> 4, sub = tid & 15;   // m 0..63, 16 cols each
    int i = m >> 1, j = jt*2 + (m & 1);
    bool valid = (m < 56);
    float mi = (valid && i < cb) ? 1.f : 0.f;
    float mj = (valid && j < cb) ? 1.f : 0.f;
    const float* ci = centers + (b*28 + (valid ? i : 0))*3;
    const float* cj = centers + (b*28 + j)*3;
    float dx = mi*ci[0] - mj*cj[0];
    float dy = mi*ci[1] - mj*cj[1];
    float dz = mi*ci[2] - mj*cj[2];
    for (int e = sub*16; e < sub*16 + 16; ++e){
      float v = valid ? (dx*Wr[e*3] + dy*Wr[e*3+1] + dz*Wr[e*3+2] + br[e]) : 0.f;
      Xb[xsw(m, e)] = f2b(v);
    }
  }
  __syncthreads();

  f32x4 Ya[2][2];
  #pragma unroll 1
  for (int l=0; l<3; ++l){
    // GEMM1: rlf @ Wgr_r^T
    GEMM_TILE64(Wgr, 768, 512);
    __syncthreads();
    // S2: rlf_lin = Y + A_i + A_j + bgr -> Xb (bf16)
    const int lb = (l*7168 + b*28)*512;
    #pragma unroll
    for (int nt=0; nt<2; ++nt){
      int n = nbase + nt*16 + col;
      float bg = bgr[n];
      #pragma unroll
      for (int rf=0; rf<2; ++rf){
        #pragma unroll
        for (int r=0; r<4; ++r){
          float v = Ya[rf][nt][r] + bg
                  + b2f(Aterm[lb + pis[rf][r]*512 + n])
                  + b2f(Aterm[lb + pjs[rf][r]*512 + 256 + n]);
          Xb[xsw(rbase + rf*16 + quad*4 + r, n)] = f2b(v);
        }
      }
    }
    __syncthreads();
    // GEMM2: rlf_lin @ Wbc^T
    GEMM_TILE64(Wbc, 256, 0);
    __syncthreads();
    // S4: rlf = tanh(c1*rlf_lin + c2*(CP+bbc)) * pv
    #pragma unroll
    for (int nt=0; nt<2; ++nt){
      int n = nbase + nt*16 + col;
      float bb = bbc[n];
      #pragma unroll
      for (int rf=0; rf<2; ++rf){
        #pragma unroll
        for (int r=0; r<4; ++r){
          int off = xsw(rbase + rf*16 + quad*4 + r, n);
          float rl = b2f(Xb[off]);
          float bez = c1*rl + c2*(Ya[rf][nt][r] + bb);
          Xb[off] = f2b(tanh_f(bez) * pv[rf][r]);
        }
      }
    }
    __syncthreads();
  }
  // S5: resa = rlf @ Wesa^T + besa -> Xb (bf16)
  GEMM_TILE64(Wesa, 256, 0);
  __syncthreads();   // all reads of rlf done before overwrite with resa
  #pragma unroll
  for (int nt=0; nt<2; ++nt){
    int n = nbase + nt*16 + col;
    float be = besa[n];
    #pragma unroll
    for (int rf=0; rf<2; ++rf){
      #pragma unroll
      for (int r=0; r<4; ++r)
        Xb[xsw(rbase + rf*16 + quad*4 + r, n)] = f2b(Ya[rf][nt][r] + be);
    }
  }
  __syncthreads();
  // gscore per row (rows < 56; stats into pad rows) + lseB per (jc,o)
  {
    int m = tid >> 4, sub = tid & 15;   // 16 threads per row, 16 cols each
    if (m < 56){
      float s = 0.f;
      for (int e = sub*16; e < sub*16 + 16; ++e){
        float wm = Wmu[e] + Wmu[256+e] + Wmu[512+e];
        s += b2f(Xb[xsw(m, e)]) * wm;
      }
      s += __shfl_xor(s, 1, 64);
      s += __shfl_xor(s, 2, 64);
      s += __shfl_xor(s, 4, 64);
      s += __shfl_xor(s, 8, 64);
      if (sub == 0)
        gsbp[m] = s*(1.f/3.f) + (bmu[0] + bmu[1] + bmu[2])*(1.f/3.f);
    }
  }
  if (tid < 512){
    int jc = tid >> 8, o = tid & 255;
    float mx = -1e30f;
    for (int i=0;i<28;++i) mx = fmaxf(mx, b2f(Xb[xsw(i*2+jc, o)]));
    float se = 0.f;
    for (int i=0;i<28;++i) se += __expf(b2f(Xb[xsw(i*2+jc, o)]) - mx);
    lseBp[jc*256 + o] = mx + __logf(se);
  }
  __syncthreads();
  if (tid < 2){
    int jc = tid;
    float mx = -1e30f;
    for (int i=0;i<28;++i) mx = fmaxf(mx, gsbp[i*2+jc]);
    float se = 0.f;
    for (int i=0;i<28;++i) se += __expf(gsbp[i*2+jc] - mx);
    lseGp[jc] = mx + __logf(se);
  }
  __syncthreads();
  // output contribution of this block's 2 j's: one atomicAdd per (i,o)
  for (int it = tid; it < 7168; it += 1024){
    int i = it >> 8, o = it & 255;
    float s = 0.f;
    #pragma unroll
    for (int jc=0; jc<2; ++jc){
      int row = i*2 + jc;
      float v = b2f(Xb[xsw(row, o)]);
      float a = 0.5f*__expf(v - lseBp[jc*256+o]) + 0.5f*__expf(gsbp[row] - lseGp[jc]);
      s += a * v;
    }
    atomicAdd(&outacc[((size_t)b*28 + i)*256 + o], s);
  }
}

// ---------------- K5: mask + write f32 ----------------
__global__ __launch_bounds__(256) void k_out(const float* __restrict__ outacc,
                                             const int* __restrict__ counts,
                                             float* __restrict__ out){
  int b = blockIdx.x / 28, i = blockIdx.x - b*28, o = threadIdx.x;
  float acc = outacc[(size_t)blockIdx.x*256 + o];
  if (i >= counts[b]) acc = 0.f;
  out[(size_t)blockIdx.x*256 + o] = acc;
}

extern "C" void kernel_launch(void* const* d_in, const int* in_sizes, int n_in,
                              void* d_out, int out_size, void* d_ws, size_t ws_size,
                              hipStream_t stream){
  const float* centers = (const float*)d_in[0];
  const float* emb     = (const float*)d_in[1];
  const int*   counts  = (const int*)d_in[2];
  const float* Wr      = (const float*)d_in[3];
  const float* br      = (const float*)d_in[4];
  const float* Wih     = (const float*)d_in[5];
  const float* Whh     = (const float*)d_in[6];
  const float* bih     = (const float*)d_in[7];
  const float* bhh     = (const float*)d_in[8];
  const float* Wgr     = (const float*)d_in[9];
  const float* bgr     = (const float*)d_in[10];
  const float* Wbc     = (const float*)d_in[11];
  const float* bbc     = (const float*)d_in[12];
  const float* alpha   = (const float*)d_in[13];
  const float* Wesa    = (const float*)d_in[14];
  const float* besa    = (const float*)d_in[15];
  const float* Wmu     = (const float*)d_in[16];
  const float* bmu     = (const float*)d_in[17];
  // d_in[18], d_in[19] (Wlv, blv) are dead at eval time.

  // ws layout (42,074,112 bytes total):
  unsigned short* olf    = (unsigned short*)d_ws;                      // 3*7168*256 bf16 = 11,010,048 B
  unsigned short* At     = (unsigned short*)((char*)d_ws + 11010048);  // 3*7168*512 bf16 = 22,020,096 B
  unsigned short* zx     = At;                                         // 7168*1024 bf16 (aliases At)
  float*          outacc = (float*)((char*)d_ws + 33030144);           // 7168*256 f32 = 7,340,032 B
  unsigned short* wcv    = (unsigned short*)((char*)d_ws + 40370176);  // 851,968 bf16 = 1,703,936 B
  unsigned short* cWih  = wcv;            // 262144
  unsigned short* cWhh  = wcv + 262144;   // 262144
  unsigned short* cWgr  = wcv + 524288;   // 196608
  unsigned short* cWbc  = wcv + 720896;   // 65536
  unsigned short* cWesa = wcv + 786432;   // 65536
  float* outp = (float*)d_out;

  hipLaunchKernelGGL(k_cvt5, dim3(3328), dim3(256), 0, stream, Wih, Whh, Wgr, Wbc, Wesa, wcv);

  hipLaunchKernelGGL(k_prep, dim3(7168), dim3(256), 0, stream, emb, counts, olf, outacc);
  // LSTM pass 1: olf0 -> olf1
  hipLaunchKernelGGL(k_xgemm, dim3(112), dim3(256), 0, stream, olf, cWih, zx);
  hipLaunchKernelGGL(k_rec,   dim3(16),  dim3(1024), 0, stream, zx, cWhh, bih, bhh, counts,
                     olf + (size_t)7168*256);
  // LSTM pass 2: olf1 -> olf2
  hipLaunchKernelGGL(k_xgemm, dim3(112), dim3(256), 0, stream, olf + (size_t)7168*256, cWih, zx);
  hipLaunchKernelGGL(k_rec,   dim3(16),  dim3(1024), 0, stream, zx, cWhh, bih, bhh, counts,
                     olf + (size_t)2*7168*256);
  hipLaunchKernelGGL(k_aterm, dim3(336), dim3(256), 0, stream, olf, cWgr, At);
  hipLaunchKernelGGL(k_mega,  dim3(3584), dim3(1024), 0, stream,
                     centers, counts, Wr, br, cWgr, bgr, cWbc, bbc, alpha,
                     cWesa, besa, Wmu, bmu, At, outacc);
  hipLaunchKernelGGL(k_out,   dim3(7168), dim3(256), 0, stream, outacc, counts, outp);
}

// Round 14
// 1742.690 us; speedup vs baseline: 1.1648x; 1.1648x over previous
//
#include <hip/hip_runtime.h>

// ObjectMsgEncoder on MI355X. f32 I/O, bf16 MFMA internally (f32 accumulate).
// R13 -> R14: waves/CU 8..16 made no difference (R9/R12/R13 all ~1000us) ->
// the shared cost is the lockstep barrier structure (17 full-drain barriers
// per k_mega block). This round: ping-pong LDS.
//  * k_mega: Xa (rlf) + Yb (rlf_lin/resa), 2 x 32KB = 65,536 B (wg max).
//    GEMM1(Xa) -> S2(write Yb) -> barrier -> GEMM2(Yb) -> S4(write Xa) ->
//    barrier: 2 barriers/layer (was 4), 10 total (was 17). S2's Aterm loads
//    overlap other waves' GEMM1.
//  * k_rec: ping-pong h-buffer Ab[2] -> 1 barrier/step (was 2).
// Tile/config otherwise identical to R12 (best: 1873 us total).

typedef __attribute__((ext_vector_type(8))) short short8;
typedef __attribute__((ext_vector_type(4))) float f32x4;

__device__ __forceinline__ float b2f(unsigned short u){
  union { unsigned int i; float f; } v; v.i = ((unsigned int)u) << 16; return v.f;
}
__device__ __forceinline__ unsigned short f2b(float f){
  union { float f; unsigned int i; } v; v.f = f;
  unsigned int i = v.i;
  unsigned int r = (i + 0x7FFFu + ((i >> 16) & 1u)) >> 16;
  return (unsigned short)r;
}
__device__ __forceinline__ float sigm(float x){ return 1.f/(1.f+__expf(-x)); }
__device__ __forceinline__ float tanh_f(float x){ float e = __expf(2.f*x); return 1.f - 2.f/(e+1.f); }
// swizzle: 8-element (16B) chunks, phys chunk = (c&24) | ((c^row)&7).
__device__ __forceinline__ int xsw(int row, int n){
  int c = n >> 3;
  int pc = (c & 24) | ((c ^ row) & 7);
  return row*256 + pc*8 + (n & 7);
}
__device__ __forceinline__ int xchunk(int row, int c){
  return row*256 + ((c & 24) | ((c ^ row) & 7))*8;
}

#define MFMA16(a,b,c) __builtin_amdgcn_mfma_f32_16x16x32_bf16((a),(b),(c),0,0,0)

// ---------------- K0: f32 -> bf16 conversion of all 5 weight matrices ----------------
__global__ __launch_bounds__(256) void k_cvt5(const float* __restrict__ s0,
                                              const float* __restrict__ s1,
                                              const float* __restrict__ s2,
                                              const float* __restrict__ s3,
                                              const float* __restrict__ s4,
                                              unsigned short* __restrict__ dst){
  int i = blockIdx.x*256 + threadIdx.x;   // grid 3328*256 = 851,968 exactly
  const float* s; int off;
  if      (i < 262144){ s = s0; off = 0; }
  else if (i < 524288){ s = s1; off = 262144; }
  else if (i < 720896){ s = s2; off = 524288; }
  else if (i < 786432){ s = s3; off = 720896; }
  else                { s = s4; off = 786432; }
  dst[i] = f2b(s[i - off]);
}

// ---------------- K1: olf0 = emb * mask (f32 -> bf16) + zero outacc ----------------
__global__ __launch_bounds__(256) void k_prep(const float* __restrict__ emb,
                                              const int* __restrict__ counts,
                                              unsigned short* __restrict__ olf,
                                              float* __restrict__ outacc){
  int bs = blockIdx.x;            // b*28+s
  int b = bs / 28; int s = bs - b*28;
  int e = threadIdx.x;
  olf[(size_t)bs*256 + e] = (s < counts[b]) ? f2b(emb[(size_t)bs*256 + e]) : (unsigned short)0;
  outacc[(size_t)bs*256 + e] = 0.f;
}

// ---------------- K2a: zx = olf_l @ Wih^T  [7168,256]@[256,1024] -> bf16 ----------------
__global__ __launch_bounds__(256) void k_xgemm(const unsigned short* __restrict__ olf,
                                               const unsigned short* __restrict__ Wih,
                                               unsigned short* __restrict__ zx){
  const int tid = threadIdx.x;
  const int wid = tid >> 6, lane = tid & 63, col = lane & 15, quad = lane >> 4;
  const int m0 = blockIdx.x*64 + wid*16;
  short8 af[8];
  #pragma unroll
  for (int kt=0; kt<8; ++kt)
    af[kt] = *(const short8*)&olf[(size_t)(m0 + col)*256 + kt*32 + quad*8];
  #pragma unroll 4
  for (int nt=0; nt<64; ++nt){
    int n = nt*16 + col;
    f32x4 acc = (f32x4){0.f,0.f,0.f,0.f};
    #pragma unroll
    for (int kt=0; kt<8; ++kt){
      short8 bf = *(const short8*)&Wih[(size_t)n*256 + kt*32 + quad*8];
      acc = MFMA16(af[kt], bf, acc);
    }
    #pragma unroll
    for (int r=0; r<4; ++r)
      zx[(size_t)(m0 + quad*4 + r)*1024 + n] = f2b(acc[r]);
  }
}

// ---------------- K2b: LSTM recurrence (16 blocks x 16 scenes, ping-pong h) ----------------
__global__ __launch_bounds__(512) void k_rec(const unsigned short* __restrict__ zx,
                                             const unsigned short* __restrict__ Whh,
                                             const float* __restrict__ bih,
                                             const float* __restrict__ bhh,
                                             const int* __restrict__ counts,
                                             unsigned short* __restrict__ olf_out){
  __shared__ unsigned short Ab[2][16*264];   // ping-pong h buffers
  const int tid = threadIdx.x;
  const int wid = tid >> 6, lane = tid & 63, col = lane & 15, quad = lane >> 4;
  const int sc0 = blockIdx.x * 16;

  float bz[4][2];
  #pragma unroll
  for (int g=0; g<4; ++g){
    #pragma unroll
    for (int tt=0; tt<2; ++tt){
      int u = wid*32 + tt*16 + col;
      bz[g][tt] = bih[g*256+u] + bhh[g*256+u];
    }
  }
  int cnt4[4];
  #pragma unroll
  for (int r=0; r<4; ++r) cnt4[r] = counts[sc0 + quad*4 + r];

  float cst[2][4];
  #pragma unroll
  for (int tt=0; tt<2; ++tt){
    #pragma unroll
    for (int r=0; r<4; ++r) cst[tt][r] = 0.f;
  }
  for (int i=tid; i<16*264; i+=512) Ab[0][i] = 0;   // h0 = 0
  __syncthreads();

  for (int t=0; t<28; ++t){
    const int cur = t & 1, nxt = cur ^ 1;
    float zxv[4][2][4];
    #pragma unroll
    for (int g=0; g<4; ++g){
      #pragma unroll
      for (int tt=0; tt<2; ++tt){
        #pragma unroll
        for (int r=0; r<4; ++r)
          zxv[g][tt][r] = b2f(zx[((size_t)(sc0 + quad*4 + r)*28 + t)*1024
                                 + g*256 + wid*32 + tt*16 + col]);
      }
    }
    f32x4 acc[4][2];
    #pragma unroll
    for (int g=0; g<4; ++g){
      #pragma unroll
      for (int tt=0; tt<2; ++tt) acc[g][tt] = (f32x4){0.f,0.f,0.f,0.f};
    }
    #pragma unroll
    for (int kt=0; kt<8; ++kt){
      short8 a = *(const short8*)&Ab[cur][col*264 + kt*32 + quad*8];
      #pragma unroll
      for (int g=0; g<4; ++g){
        #pragma unroll
        for (int tt=0; tt<2; ++tt){
          int n = g*256 + wid*32 + tt*16 + col;
          short8 bf = *(const short8*)&Whh[(size_t)n*256 + kt*32 + quad*8];
          acc[g][tt] = MFMA16(a, bf, acc[g][tt]);
        }
      }
    }
    // no barrier: writes go to Ab[nxt], readers use Ab[cur]
    #pragma unroll
    for (int tt=0; tt<2; ++tt){
      #pragma unroll
      for (int r=0; r<4; ++r){
        int s = quad*4 + r;
        int u = wid*32 + tt*16 + col;
        float zi = acc[0][tt][r] + zxv[0][tt][r] + bz[0][tt];
        float zf = acc[1][tt][r] + zxv[1][tt][r] + bz[1][tt];
        float zg = acc[2][tt][r] + zxv[2][tt][r] + bz[2][tt];
        float zo = acc[3][tt][r] + zxv[3][tt][r] + bz[3][tt];
        float cc = sigm(zf)*cst[tt][r] + sigm(zi)*tanh_f(zg);
        cst[tt][r] = cc;
        float hh = sigm(zo)*tanh_f(cc);
        unsigned short hb = f2b(hh);
        Ab[nxt][s*264 + u] = hb;                              // raw h feeds recurrence
        olf_out[((size_t)(sc0+s)*28 + t)*256 + u] = (t < cnt4[r]) ? hb : (unsigned short)0;
      }
    }
    __syncthreads();   // Ab[nxt] complete before step t+1 reads it
  }
}

// ---------------- K3: A-terms, [21504,256]@[256,512] -> bf16 ----------------
__global__ __launch_bounds__(256) void k_aterm(const unsigned short* __restrict__ olf,
                                               const unsigned short* __restrict__ Wgr,
                                               unsigned short* __restrict__ Aout){
  const int tid = threadIdx.x;
  const int wid = tid >> 6, lane = tid & 63, col = lane & 15, quad = lane >> 4;
  const int m0 = blockIdx.x*64 + wid*16;
  short8 af[8];
  #pragma unroll
  for (int kt=0; kt<8; ++kt)
    af[kt] = *(const short8*)&olf[(size_t)(m0 + col)*256 + kt*32 + quad*8];
  #pragma unroll 4
  for (int nt=0; nt<32; ++nt){
    int n = nt*16 + col;   // n<256: A_i (Wgr cols 0..255); else A_j (cols 256..511)
    const unsigned short* wb = (nt < 16) ? (Wgr + n*768) : (Wgr + (n-256)*768 + 256);
    f32x4 acc = (f32x4){0.f,0.f,0.f,0.f};
    #pragma unroll
    for (int kt=0; kt<8; ++kt){
      short8 bf = *(const short8*)&wb[kt*32 + quad*8];
      acc = MFMA16(af[kt], bf, acc);
    }
    #pragma unroll
    for (int r=0; r<4; ++r)
      Aout[(size_t)(m0 + quad*4 + r)*512 + nt*16 + col] = f2b(acc[r]);
  }
}

// ---------------- K4: fused per-(scene, j-pair), ping-pong LDS ----------------
// 3584 blocks x 512 thr (8 waves). Row p = i*2 + jc (i<28, jc<2) -> 56 rows
// padded to 64. Wave wv owns cols wv*32..+31 for all 64 rows (4 row-frags x
// 2 col-frags, kt chunks of 2). Xa = rlf, Yb = rlf_lin/resa: 2 x 32,768 B.
#define GEMM_TILE64(SRC, WPTR, WSTRIDE, WOFF)                                       \
  {                                                                                 \
    _Pragma("unroll")                                                               \
    for (int rf=0; rf<4; ++rf){ Ya[rf][0]=(f32x4){0.f,0.f,0.f,0.f};                 \
                                Ya[rf][1]=(f32x4){0.f,0.f,0.f,0.f}; }               \
    _Pragma("unroll 1")                                                             \
    for (int kc=0; kc<4; ++kc){                                                     \
      short8 av[2][4], bv[2][2];                                                    \
      _Pragma("unroll")                                                             \
      for (int u=0; u<2; ++u){                                                      \
        int kt = kc*2 + u; int c = kt*4 + quad;                                     \
        _Pragma("unroll")                                                           \
        for (int rf=0; rf<4; ++rf)                                                  \
          av[u][rf] = *(const short8*)&(SRC)[xchunk(rf*16+col, c)];                 \
        bv[u][0] = *(const short8*)&(WPTR)[(nbase+col)*(WSTRIDE) + (WOFF) + kt*32 + quad*8];    \
        bv[u][1] = *(const short8*)&(WPTR)[(nbase+16+col)*(WSTRIDE) + (WOFF) + kt*32 + quad*8]; \
      }                                                                             \
      _Pragma("unroll")                                                             \
      for (int u=0; u<2; ++u){                                                      \
        _Pragma("unroll")                                                           \
        for (int rf=0; rf<4; ++rf){                                                 \
          Ya[rf][0] = MFMA16(av[u][rf], bv[u][0], Ya[rf][0]);                       \
          Ya[rf][1] = MFMA16(av[u][rf], bv[u][1], Ya[rf][1]);                       \
        }                                                                           \
      }                                                                             \
    }                                                                               \
  }

__global__ __launch_bounds__(512) void k_mega(
    const float* __restrict__ centers, const int* __restrict__ counts,
    const float* __restrict__ Wr, const float* __restrict__ br,
    const unsigned short* __restrict__ Wgr, const float* __restrict__ bgr,
    const unsigned short* __restrict__ Wbc, const float* __restrict__ bbc,
    const float* __restrict__ alpha,
    const unsigned short* __restrict__ Wesa, const float* __restrict__ besa,
    const float* __restrict__ Wmu, const float* __restrict__ bmu,
    const unsigned short* __restrict__ Aterm, float* __restrict__ outacc){
  __shared__ unsigned short Xa[64*256];    // rlf; rows 56..63 pad -> stats later
  __shared__ unsigned short Yb[64*256];    // rlf_lin / resa
  float* lseBp = (float*)&Xa[56*256];      // 512 f32 [jc*256+o]
  float* gsbp  = (float*)&Xa[60*256];      // 64 f32 per row p
  float* lseGp = (float*)&Xa[60*256+128];  // 2 f32 per jc
  const int tid = threadIdx.x;
  const int wv = tid >> 6;          // 0..7 -> col slice
  const int lane = tid & 63, col = lane & 15, quad = lane >> 4;
  const int b = blockIdx.x / 14, jt = blockIdx.x - b*14;   // j = jt*2 + jc
  const int cb = counts[b];
  const int nbase = wv*32;

  float av_ = alpha[0];
  float tv = sigm(av_);
  float c1 = (1.f-tv)*(1.f-tv) + tv*tv;
  float c2 = 2.f*tv*(1.f-tv);

  int pis[4][4], pjs[4][4]; float pv[4][4];
  #pragma unroll
  for (int rf=0; rf<4; ++rf){
    #pragma unroll
    for (int r=0; r<4; ++r){
      int row = rf*16 + quad*4 + r;
      int i = row >> 1;
      pis[rf][r] = (i < 27) ? i : 27;
      pjs[rf][r] = jt*2 + (row & 1);
      pv[rf][r] = (row < 56 && i < cb && pjs[rf][r] < cb) ? 1.f : 0.f;
    }
  }
  // S0: rlf0[row] -> Xa ; pad rows = 0
  {
    int m = tid >> 3, sub = tid & 7;   // m 0..63, 32 cols each
    int i = m >> 1, j = jt*2 + (m & 1);
    bool valid = (m < 56);
    float mi = (valid && i < cb) ? 1.f : 0.f;
    float mj = (valid && j < cb) ? 1.f : 0.f;
    const float* ci = centers + (b*28 + (valid ? i : 0))*3;
    const float* cj = centers + (b*28 + j)*3;
    float dx = mi*ci[0] - mj*cj[0];
    float dy = mi*ci[1] - mj*cj[1];
    float dz = mi*ci[2] - mj*cj[2];
    for (int e = sub*32; e < sub*32 + 32; ++e){
      float v = valid ? (dx*Wr[e*3] + dy*Wr[e*3+1] + dz*Wr[e*3+2] + br[e]) : 0.f;
      Xa[xsw(m, e)] = f2b(v);
    }
  }
  __syncthreads();

  f32x4 Ya[4][2];
  #pragma unroll 1
  for (int l=0; l<3; ++l){
    // GEMM1: rlf(Xa) @ Wgr_r^T  -- then S2 writes Yb (no barrier in between)
    GEMM_TILE64(Xa, Wgr, 768, 512);
    // S2: rlf_lin = Y + A_i + A_j + bgr -> Yb (bf16)
    const int lb = (l*7168 + b*28)*512;
    #pragma unroll
    for (int nt=0; nt<2; ++nt){
      int n = nbase + nt*16 + col;
      float bg = bgr[n];
      #pragma unroll
      for (int rf=0; rf<4; ++rf){
        #pragma unroll
        for (int r=0; r<4; ++r){
          float v = Ya[rf][nt][r] + bg
                  + b2f(Aterm[lb + pis[rf][r]*512 + n])
                  + b2f(Aterm[lb + pjs[rf][r]*512 + 256 + n]);
          Yb[xsw(rf*16 + quad*4 + r, n)] = f2b(v);
        }
      }
    }
    __syncthreads();   // Yb complete before GEMM2 reads it
    // GEMM2: rlf_lin(Yb) @ Wbc^T -- then S4 writes Xa (no barrier in between)
    GEMM_TILE64(Yb, Wbc, 256, 0);
    // S4: rlf = tanh(c1*rlf_lin + c2*(CP+bbc)) * pv -> Xa (rlf_lin re-read from
    // this thread's own Yb slots -- no cross-wave dependency)
    #pragma unroll
    for (int nt=0; nt<2; ++nt){
      int n = nbase + nt*16 + col;
      float bb = bbc[n];
      #pragma unroll
      for (int rf=0; rf<4; ++rf){
        #pragma unroll
        for (int r=0; r<4; ++r){
          int off = xsw(rf*16 + quad*4 + r, n);
          float rl = b2f(Yb[off]);
          float bez = c1*rl + c2*(Ya[rf][nt][r] + bb);
          Xa[off] = f2b(tanh_f(bez) * pv[rf][r]);
        }
      }
    }
    __syncthreads();   // Xa complete before next GEMM1 (also fences GEMM2's Yb reads vs next S2)
  }
  // S5: resa = rlf(Xa) @ Wesa^T + besa -> Yb (GEMM2-l2's Yb reads fenced by last barrier)
  GEMM_TILE64(Xa, Wesa, 256, 0);
  #pragma unroll
  for (int nt=0; nt<2; ++nt){
    int n = nbase + nt*16 + col;
    float be = besa[n];
    #pragma unroll
    for (int rf=0; rf<4; ++rf){
      #pragma unroll
      for (int r=0; r<4; ++r)
        Yb[xsw(rf*16 + quad*4 + r, n)] = f2b(Ya[rf][nt][r] + be);
    }
  }
  __syncthreads();   // resa (Yb) complete; Xa now dead -> stats go into Xa pads
  // gscore per row (rows < 56) + lseB per (jc,o), all read Yb
  {
    int m = tid >> 3, sub = tid & 7;   // 8 threads per row, 32 cols each
    if (m < 56){
      float s = 0.f;
      for (int e = sub*32; e < sub*32 + 32; ++e){
        float wm = Wmu[e] + Wmu[256+e] + Wmu[512+e];
        s += b2f(Yb[xsw(m, e)]) * wm;
      }
      s += __shfl_xor(s, 1, 64);
      s += __shfl_xor(s, 2, 64);
      s += __shfl_xor(s, 4, 64);
      if (sub == 0)
        gsbp[m] = s*(1.f/3.f) + (bmu[0] + bmu[1] + bmu[2])*(1.f/3.f);
    }
  }
  {
    int jc = tid >> 8, o = tid & 255;  // all 512 threads
    float mx = -1e30f;
    for (int i=0;i<28;++i) mx = fmaxf(mx, b2f(Yb[xsw(i*2+jc, o)]));
    float se = 0.f;
    for (int i=0;i<28;++i) se += __expf(b2f(Yb[xsw(i*2+jc, o)]) - mx);
    lseBp[jc*256 + o] = mx + __logf(se);
  }
  __syncthreads();
  if (tid < 2){
    int jc = tid;
    float mx = -1e30f;
    for (int i=0;i<28;++i) mx = fmaxf(mx, gsbp[i*2+jc]);
    float se = 0.f;
    for (int i=0;i<28;++i) se += __expf(gsbp[i*2+jc] - mx);
    lseGp[jc] = mx + __logf(se);
  }
  __syncthreads();
  // output contribution of this block's 2 j's: one atomicAdd per (i,o)
  for (int it = tid; it < 7168; it += 512){
    int i = it >> 8, o = it & 255;
    float s = 0.f;
    #pragma unroll
    for (int jc=0; jc<2; ++jc){
      int row = i*2 + jc;
      float v = b2f(Yb[xsw(row, o)]);
      float a = 0.5f*__expf(v - lseBp[jc*256+o]) + 0.5f*__expf(gsbp[row] - lseGp[jc]);
      s += a * v;
    }
    atomicAdd(&outacc[((size_t)b*28 + i)*256 + o], s);
  }
}

// ---------------- K5: mask + write f32 ----------------
__global__ __launch_bounds__(256) void k_out(const float* __restrict__ outacc,
                                             const int* __restrict__ counts,
                                             float* __restrict__ out){
  int b = blockIdx.x / 28, i = blockIdx.x - b*28, o = threadIdx.x;
  float acc = outacc[(size_t)blockIdx.x*256 + o];
  if (i >= counts[b]) acc = 0.f;
  out[(size_t)blockIdx.x*256 + o] = acc;
}

extern "C" void kernel_launch(void* const* d_in, const int* in_sizes, int n_in,
                              void* d_out, int out_size, void* d_ws, size_t ws_size,
                              hipStream_t stream){
  const float* centers = (const float*)d_in[0];
  const float* emb     = (const float*)d_in[1];
  const int*   counts  = (const int*)d_in[2];
  const float* Wr      = (const float*)d_in[3];
  const float* br      = (const float*)d_in[4];
  const float* Wih     = (const float*)d_in[5];
  const float* Whh     = (const float*)d_in[6];
  const float* bih     = (const float*)d_in[7];
  const float* bhh     = (const float*)d_in[8];
  const float* Wgr     = (const float*)d_in[9];
  const float* bgr     = (const float*)d_in[10];
  const float* Wbc     = (const float*)d_in[11];
  const float* bbc     = (const float*)d_in[12];
  const float* alpha   = (const float*)d_in[13];
  const float* Wesa    = (const float*)d_in[14];
  const float* besa    = (const float*)d_in[15];
  const float* Wmu     = (const float*)d_in[16];
  const float* bmu     = (const float*)d_in[17];
  // d_in[18], d_in[19] (Wlv, blv) are dead at eval time.

  // ws layout (42,074,112 bytes total):
  unsigned short* olf    = (unsigned short*)d_ws;                      // 3*7168*256 bf16 = 11,010,048 B
  unsigned short* At     = (unsigned short*)((char*)d_ws + 11010048);  // 3*7168*512 bf16 = 22,020,096 B
  unsigned short* zx     = At;                                         // 7168*1024 bf16 (aliases At)
  float*          outacc = (float*)((char*)d_ws + 33030144);           // 7168*256 f32 = 7,340,032 B
  unsigned short* wcv    = (unsigned short*)((char*)d_ws + 40370176);  // 851,968 bf16 = 1,703,936 B
  unsigned short* cWih  = wcv;            // 262144
  unsigned short* cWhh  = wcv + 262144;   // 262144
  unsigned short* cWgr  = wcv + 524288;   // 196608
  unsigned short* cWbc  = wcv + 720896;   // 65536
  unsigned short* cWesa = wcv + 786432;   // 65536
  float* outp = (float*)d_out;

  hipLaunchKernelGGL(k_cvt5, dim3(3328), dim3(256), 0, stream, Wih, Whh, Wgr, Wbc, Wesa, wcv);

  hipLaunchKernelGGL(k_prep, dim3(7168), dim3(256), 0, stream, emb, counts, olf, outacc);
  // LSTM pass 1: olf0 -> olf1
  hipLaunchKernelGGL(k_xgemm, dim3(112), dim3(256), 0, stream, olf, cWih, zx);
  hipLaunchKernelGGL(k_rec,   dim3(16),  dim3(512), 0, stream, zx, cWhh, bih, bhh, counts,
                     olf + (size_t)7168*256);
  // LSTM pass 2: olf1 -> olf2
  hipLaunchKernelGGL(k_xgemm, dim3(112), dim3(256), 0, stream, olf + (size_t)7168*256, cWih, zx);
  hipLaunchKernelGGL(k_rec,   dim3(16),  dim3(512), 0, stream, zx, cWhh, bih, bhh, counts,
                     olf + (size_t)2*7168*256);
  hipLaunchKernelGGL(k_aterm, dim3(336), dim3(256), 0, stream, olf, cWgr, At);
  hipLaunchKernelGGL(k_mega,  dim3(3584), dim3(512), 0, stream,
                     centers, counts, Wr, br, cWgr, bgr, cWbc, bbc, alpha,
                     cWesa, besa, Wmu, bmu, At, outacc);
  hipLaunchKernelGGL(k_out,   dim3(7168), dim3(256), 0, stream, outacc, counts, outp);
}